// Round 4
// baseline (340.649 us; speedup 1.0000x reference)
//
#include <hip/hip_runtime.h>

#define DIM    64
#define NEMB   1024
#define HW     4096      // 64*64
#define NPIX   131072    // 32*64*64
#define NOUT   8388608   // 32*64*64*64
#define NSPLIT 4
#define CPS    (NEMB / NSPLIT)   // 256 codes per split

// ---------------------------------------------------------------------------
// prep: eT[j][d] = embed[d][j]  (code rows contiguous -> scalar s_load path),
// cn[j] = ||e_j||^2 with numpy axis-0 semantics (rounded muls, sequential adds)
// ---------------------------------------------------------------------------
__global__ __launch_bounds__(256) void prep_kernel(const float* __restrict__ embed,
                                                   float* __restrict__ eT,
                                                   float* __restrict__ cn) {
    const int j = blockIdx.x * 256 + threadIdx.x;
    if (j >= NEMB) return;
    float v[DIM];
#pragma unroll
    for (int d = 0; d < DIM; ++d) {
        v[d] = embed[d * NEMB + j];
        eT[j * DIM + d] = v[d];
    }
    float s = __fmul_rn(v[0], v[0]);
#pragma unroll
    for (int d = 1; d < DIM; ++d)
        s = __fadd_rn(s, __fmul_rn(v[d], v[d]));
    cn[j] = s;
}

// ---------------------------------------------------------------------------
// scan: block = 256 pixels, blockIdx.y = code split (block-uniform -> e rows
// via scalar s_load pipe). x[64] is PINNED in VGPRs via an opaque asm
// barrier: without it the compiler (VGPR=44) rematerializes the x loads
// inside the j-loop, re-issuing 64 VMEM loads per 4 codes (R2: 335us).
// Arithmetic identical to the R0-passing kernel. Result: packed
// (dist_bits<<32 | idx) so u64-min = (min dist, first-occurrence tie).
// ---------------------------------------------------------------------------
__global__ __launch_bounds__(256, 3) void scan_kernel(const float* __restrict__ X,
                                                      const float* __restrict__ eT,
                                                      const float* __restrict__ cn,
                                                      unsigned long long* __restrict__ cand) {
    const int tid = threadIdx.x;
    const int pix = blockIdx.x * 256 + tid;
    const int b   = pix >> 12;
    const int p   = pix & 4095;
    const float* xb = X + (size_t)b * (DIM * HW) + p;

    float x[DIM];
#pragma unroll
    for (int d = 0; d < DIM; ++d) x[d] = xb[(size_t)d * HW];   // coalesced per d
    // pin: forbid rematerialization of the x loads inside the j-loop
#pragma unroll
    for (int d = 0; d < DIM; ++d) asm volatile("" : "+v"(x[d]));

    // ||f||^2, numpy pairwise 8-accumulator pattern (n=64)
    float r[8];
#pragma unroll
    for (int k = 0; k < 8; ++k) r[k] = __fmul_rn(x[k], x[k]);
#pragma unroll
    for (int i = 8; i < DIM; i += 8)
#pragma unroll
        for (int k = 0; k < 8; ++k)
            r[k] = __fadd_rn(r[k], __fmul_rn(x[i + k], x[i + k]));
    const float ff = __fadd_rn(
        __fadd_rn(__fadd_rn(r[0], r[1]), __fadd_rn(r[2], r[3])),
        __fadd_rn(__fadd_rn(r[4], r[5]), __fadd_rn(r[6], r[7])));

    float minv = __builtin_inff();
    int   mini = 0;
    const int jbase = blockIdx.y * CPS;   // block-uniform

#pragma unroll 1
    for (int jj = 0; jj < CPS; jj += 4) {
        const int j0 = jbase + jj;
        const float* e = eT + (size_t)j0 * DIM;   // block-uniform -> s_load
        float a0 = 0.f, a1 = 0.f, a2 = 0.f, a3 = 0.f;
#pragma unroll
        for (int d = 0; d < DIM; ++d) {
            const float xd = x[d];
            a0 = fmaf(xd, e[d],           a0);   // v_fmac_f32 vacc, s_e, v_x
            a1 = fmaf(xd, e[DIM + d],     a1);
            a2 = fmaf(xd, e[2 * DIM + d], a2);
            a3 = fmaf(xd, e[3 * DIM + d], a3);
        }
        const float d0 = __fadd_rn(__fsub_rn(ff, __fmul_rn(2.f, a0)), cn[j0 + 0]);
        const float d1 = __fadd_rn(__fsub_rn(ff, __fmul_rn(2.f, a1)), cn[j0 + 1]);
        const float d2 = __fadd_rn(__fsub_rn(ff, __fmul_rn(2.f, a2)), cn[j0 + 2]);
        const float d3 = __fadd_rn(__fsub_rn(ff, __fmul_rn(2.f, a3)), cn[j0 + 3]);
        if (d0 < minv) { minv = d0; mini = j0 + 0; }
        if (d1 < minv) { minv = d1; mini = j0 + 1; }
        if (d2 < minv) { minv = d2; mini = j0 + 2; }
        if (d3 < minv) { minv = d3; mini = j0 + 3; }
    }

    cand[(size_t)blockIdx.y * NPIX + pix] =
        ((unsigned long long)__float_as_uint(minv) << 32) | (unsigned)mini;
}

// ---------------------------------------------------------------------------
// finish: merge NSPLIT candidates per pixel, gather code, write q_out =
// x + (q - x), accumulate MSE loss.
// ---------------------------------------------------------------------------
__global__ __launch_bounds__(256) void finish_kernel(const float* __restrict__ X,
                                                     const float* __restrict__ embed,
                                                     const unsigned long long* __restrict__ cand,
                                                     float* __restrict__ OUT,
                                                     float* __restrict__ loss) {
    const int tid = threadIdx.x;
    const int pix = blockIdx.x * 256 + tid;
    const int b   = pix >> 12;
    const int p   = pix & 4095;

    unsigned long long m = cand[pix];
#pragma unroll
    for (int s = 1; s < NSPLIT; ++s) {
        const unsigned long long c = cand[(size_t)s * NPIX + pix];
        m = (c < m) ? c : m;
    }
    const int idx = (int)(m & 0xFFFFFFFFull);

    const float* xb  = X   + (size_t)b * (DIM * HW) + p;
    float*      outb = OUT + (size_t)b * (DIM * HW) + p;
    float lerr = 0.f;
#pragma unroll
    for (int d = 0; d < DIM; ++d) {
        const float qv = embed[d * NEMB + idx];   // 256 KB, L2-resident gather
        const float xv = xb[(size_t)d * HW];
        const float df = __fsub_rn(qv, xv);
        outb[(size_t)d * HW] = __fadd_rn(xv, df); // coalesced across lanes
        lerr = fmaf(df, df, lerr);
    }

    __shared__ float sred[256];
    sred[tid] = lerr;
    __syncthreads();
#pragma unroll
    for (int s = 128; s > 0; s >>= 1) {
        if (tid < s) sred[tid] += sred[tid + s];
        __syncthreads();
    }
    if (tid == 0)
        atomicAdd(loss, sred[0] * (1.0f / (float)NOUT));
}

// ---------------------------------------------------------------------------
// fallback (ws too small for candidates): fused structure, same pin fix.
// ---------------------------------------------------------------------------
__global__ __launch_bounds__(256, 3) void vq_full(const float* __restrict__ X,
                                                  const float* __restrict__ embed,
                                                  const float* __restrict__ eT,
                                                  const float* __restrict__ cn,
                                                  float* __restrict__ OUT,
                                                  float* __restrict__ loss) {
    const int tid = threadIdx.x;
    const int pix = blockIdx.x * 256 + tid;
    const int b   = pix >> 12;
    const int p   = pix & 4095;
    const float* xb = X + (size_t)b * (DIM * HW) + p;

    float x[DIM];
#pragma unroll
    for (int d = 0; d < DIM; ++d) x[d] = xb[(size_t)d * HW];
#pragma unroll
    for (int d = 0; d < DIM; ++d) asm volatile("" : "+v"(x[d]));

    float r[8];
#pragma unroll
    for (int k = 0; k < 8; ++k) r[k] = __fmul_rn(x[k], x[k]);
#pragma unroll
    for (int i = 8; i < DIM; i += 8)
#pragma unroll
        for (int k = 0; k < 8; ++k)
            r[k] = __fadd_rn(r[k], __fmul_rn(x[i + k], x[i + k]));
    const float ff = __fadd_rn(
        __fadd_rn(__fadd_rn(r[0], r[1]), __fadd_rn(r[2], r[3])),
        __fadd_rn(__fadd_rn(r[4], r[5]), __fadd_rn(r[6], r[7])));

    float minv = __builtin_inff();
    int   mini = 0;
#pragma unroll 1
    for (int j0 = 0; j0 < NEMB; j0 += 4) {
        const float* e = eT + (size_t)j0 * DIM;
        float a0 = 0.f, a1 = 0.f, a2 = 0.f, a3 = 0.f;
#pragma unroll
        for (int d = 0; d < DIM; ++d) {
            const float xd = x[d];
            a0 = fmaf(xd, e[d],           a0);
            a1 = fmaf(xd, e[DIM + d],     a1);
            a2 = fmaf(xd, e[2 * DIM + d], a2);
            a3 = fmaf(xd, e[3 * DIM + d], a3);
        }
        const float d0 = __fadd_rn(__fsub_rn(ff, __fmul_rn(2.f, a0)), cn[j0 + 0]);
        const float d1 = __fadd_rn(__fsub_rn(ff, __fmul_rn(2.f, a1)), cn[j0 + 1]);
        const float d2 = __fadd_rn(__fsub_rn(ff, __fmul_rn(2.f, a2)), cn[j0 + 2]);
        const float d3 = __fadd_rn(__fsub_rn(ff, __fmul_rn(2.f, a3)), cn[j0 + 3]);
        if (d0 < minv) { minv = d0; mini = j0 + 0; }
        if (d1 < minv) { minv = d1; mini = j0 + 1; }
        if (d2 < minv) { minv = d2; mini = j0 + 2; }
        if (d3 < minv) { minv = d3; mini = j0 + 3; }
    }

    float lerr = 0.f;
    float* outb = OUT + (size_t)b * (DIM * HW) + p;
#pragma unroll
    for (int d = 0; d < DIM; ++d) {
        const float qv = embed[d * NEMB + mini];
        const float df = __fsub_rn(qv, x[d]);
        outb[(size_t)d * HW] = __fadd_rn(x[d], df);
        lerr = fmaf(df, df, lerr);
    }

    __shared__ float sred[256];
    sred[tid] = lerr;
    __syncthreads();
#pragma unroll
    for (int s = 128; s > 0; s >>= 1) {
        if (tid < s) sred[tid] += sred[tid + s];
        __syncthreads();
    }
    if (tid == 0)
        atomicAdd(loss, sred[0] * (1.0f / (float)NOUT));
}

extern "C" void kernel_launch(void* const* d_in, const int* in_sizes, int n_in,
                              void* d_out, int out_size, void* d_ws, size_t ws_size,
                              hipStream_t stream) {
    const float* X = (const float*)d_in[0];
    const float* E = (const float*)d_in[1];
    float* OUT  = (float*)d_out;
    float* loss = OUT + NOUT;

    // ws layout: [cand: NSPLIT*NPIX u64][eT: 1024*64 f32][cn: 1024 f32]
    const size_t cand_bytes = (size_t)NSPLIT * NPIX * 8;
    const size_t need = cand_bytes + (size_t)(NEMB * DIM + NEMB) * 4;

    hipMemsetAsync(loss, 0, sizeof(float), stream);

    if (ws_size >= need) {
        unsigned long long* cand = (unsigned long long*)d_ws;
        float* eT = (float*)((char*)d_ws + cand_bytes);
        float* cn = eT + NEMB * DIM;
        prep_kernel<<<NEMB / 256, 256, 0, stream>>>(E, eT, cn);
        scan_kernel<<<dim3(NPIX / 256, NSPLIT), 256, 0, stream>>>(X, eT, cn, cand);
        finish_kernel<<<NPIX / 256, 256, 0, stream>>>(X, E, cand, OUT, loss);
    } else {
        float* eT = (float*)d_ws;
        float* cn = eT + NEMB * DIM;
        prep_kernel<<<NEMB / 256, 256, 0, stream>>>(E, eT, cn);
        vq_full<<<NPIX / 256, 256, 0, stream>>>(X, E, eT, cn, OUT, loss);
    }
}

// Round 5
// 329.358 us; speedup vs baseline: 1.0343x; 1.0343x over previous
//
#include <hip/hip_runtime.h>

#define DIM    64
#define NEMB   1024
#define HW     4096      // 64*64
#define NPIX   131072    // 32*64*64
#define NOUT   8388608   // 32*64*64*64
#define NSPLIT 4
#define CPS    (NEMB / NSPLIT)   // 256 codes per split

// ---------------------------------------------------------------------------
// prep: eT[j][d] = embed[d][j]  (code rows contiguous -> scalar s_load path),
// cn[j] = ||e_j||^2 with numpy axis-0 semantics (rounded muls, sequential adds)
// ---------------------------------------------------------------------------
__global__ __launch_bounds__(256) void prep_kernel(const float* __restrict__ embed,
                                                   float* __restrict__ eT,
                                                   float* __restrict__ cn) {
    const int j = blockIdx.x * 256 + threadIdx.x;
    if (j >= NEMB) return;
    float v[DIM];
#pragma unroll
    for (int d = 0; d < DIM; ++d) {
        v[d] = embed[d * NEMB + j];
        eT[j * DIM + d] = v[d];
    }
    float s = __fmul_rn(v[0], v[0]);
#pragma unroll
    for (int d = 1; d < DIM; ++d)
        s = __fadd_rn(s, __fmul_rn(v[d], v[d]));
    cn[j] = s;
}

// ---------------------------------------------------------------------------
// scan: block = 256 pixels, blockIdx.y = code split (block-uniform -> e rows
// via scalar s_load pipe).
//
// x[64] is loaded via asm volatile global_load_dword: a volatile-asm def is
// non-rematerializable and non-CSE-able, so regalloc MUST keep all 64 values
// in VGPRs across the j-loop. (R2/R3 showed the compiler otherwise re-issues
// the x loads every 4-code group: VGPR=44, 335us.) Rule #18: hand-issued
// loads need explicit vmcnt(0) + sched_barrier(0) before first use.
//
// Distance arithmetic identical to the R0-passing kernel. Result: packed
// (dist_bits<<32 | idx) so u64-min = (min dist, first-occurrence tie).
// ---------------------------------------------------------------------------
__global__ __launch_bounds__(256, 4) void scan_kernel(const float* __restrict__ X,
                                                      const float* __restrict__ eT,
                                                      const float* __restrict__ cn,
                                                      unsigned long long* __restrict__ cand) {
    const int tid = threadIdx.x;
    const int pix = blockIdx.x * 256 + tid;
    const int b   = pix >> 12;
    const int p   = pix & 4095;
    const float* xb = X + (size_t)b * (DIM * HW) + p;

    float x[DIM];
#pragma unroll
    for (int d = 0; d < DIM; ++d) {
        const float* a = xb + (size_t)d * HW;        // coalesced across lanes
        asm volatile("global_load_dword %0, %1, off"
                     : "=v"(x[d]) : "v"(a));
    }
    asm volatile("s_waitcnt vmcnt(0)" ::: "memory");
    __builtin_amdgcn_sched_barrier(0);               // rule #18: no hoist past wait

    // ||f||^2, numpy pairwise 8-accumulator pattern (n=64)
    float r[8];
#pragma unroll
    for (int k = 0; k < 8; ++k) r[k] = __fmul_rn(x[k], x[k]);
#pragma unroll
    for (int i = 8; i < DIM; i += 8)
#pragma unroll
        for (int k = 0; k < 8; ++k)
            r[k] = __fadd_rn(r[k], __fmul_rn(x[i + k], x[i + k]));
    const float ff = __fadd_rn(
        __fadd_rn(__fadd_rn(r[0], r[1]), __fadd_rn(r[2], r[3])),
        __fadd_rn(__fadd_rn(r[4], r[5]), __fadd_rn(r[6], r[7])));

    float minv = __builtin_inff();
    int   mini = 0;
    const int jbase = blockIdx.y * CPS;   // block-uniform

#pragma unroll 1
    for (int jj = 0; jj < CPS; jj += 4) {
        const int j0 = jbase + jj;
        const float* e = eT + (size_t)j0 * DIM;   // block-uniform -> s_load
        float a0 = 0.f, a1 = 0.f, a2 = 0.f, a3 = 0.f;
#pragma unroll
        for (int d = 0; d < DIM; ++d) {
            const float xd = x[d];
            a0 = fmaf(xd, e[d],           a0);   // v_fmac_f32 vacc, s_e, v_x
            a1 = fmaf(xd, e[DIM + d],     a1);
            a2 = fmaf(xd, e[2 * DIM + d], a2);
            a3 = fmaf(xd, e[3 * DIM + d], a3);
        }
        const float d0 = __fadd_rn(__fsub_rn(ff, __fmul_rn(2.f, a0)), cn[j0 + 0]);
        const float d1 = __fadd_rn(__fsub_rn(ff, __fmul_rn(2.f, a1)), cn[j0 + 1]);
        const float d2 = __fadd_rn(__fsub_rn(ff, __fmul_rn(2.f, a2)), cn[j0 + 2]);
        const float d3 = __fadd_rn(__fsub_rn(ff, __fmul_rn(2.f, a3)), cn[j0 + 3]);
        if (d0 < minv) { minv = d0; mini = j0 + 0; }
        if (d1 < minv) { minv = d1; mini = j0 + 1; }
        if (d2 < minv) { minv = d2; mini = j0 + 2; }
        if (d3 < minv) { minv = d3; mini = j0 + 3; }
    }

    cand[(size_t)blockIdx.y * NPIX + pix] =
        ((unsigned long long)__float_as_uint(minv) << 32) | (unsigned)mini;
}

// ---------------------------------------------------------------------------
// finish: merge NSPLIT candidates per pixel, gather code, write q_out =
// x + (q - x), accumulate MSE loss.
// ---------------------------------------------------------------------------
__global__ __launch_bounds__(256) void finish_kernel(const float* __restrict__ X,
                                                     const float* __restrict__ embed,
                                                     const unsigned long long* __restrict__ cand,
                                                     float* __restrict__ OUT,
                                                     float* __restrict__ loss) {
    const int tid = threadIdx.x;
    const int pix = blockIdx.x * 256 + tid;
    const int b   = pix >> 12;
    const int p   = pix & 4095;

    unsigned long long m = cand[pix];
#pragma unroll
    for (int s = 1; s < NSPLIT; ++s) {
        const unsigned long long c = cand[(size_t)s * NPIX + pix];
        m = (c < m) ? c : m;
    }
    const int idx = (int)(m & 0xFFFFFFFFull);

    const float* xb  = X   + (size_t)b * (DIM * HW) + p;
    float*      outb = OUT + (size_t)b * (DIM * HW) + p;
    float lerr = 0.f;
#pragma unroll
    for (int d = 0; d < DIM; ++d) {
        const float qv = embed[d * NEMB + idx];   // 256 KB, L2-resident gather
        const float xv = xb[(size_t)d * HW];
        const float df = __fsub_rn(qv, xv);
        outb[(size_t)d * HW] = __fadd_rn(xv, df); // coalesced across lanes
        lerr = fmaf(df, df, lerr);
    }

    __shared__ float sred[256];
    sred[tid] = lerr;
    __syncthreads();
#pragma unroll
    for (int s = 128; s > 0; s >>= 1) {
        if (tid < s) sred[tid] += sred[tid + s];
        __syncthreads();
    }
    if (tid == 0)
        atomicAdd(loss, sred[0] * (1.0f / (float)NOUT));
}

// ---------------------------------------------------------------------------
// fallback (ws too small for candidates): fused structure, full 1024 scan.
// ---------------------------------------------------------------------------
__global__ __launch_bounds__(256, 4) void vq_full(const float* __restrict__ X,
                                                  const float* __restrict__ embed,
                                                  const float* __restrict__ eT,
                                                  const float* __restrict__ cn,
                                                  float* __restrict__ OUT,
                                                  float* __restrict__ loss) {
    const int tid = threadIdx.x;
    const int pix = blockIdx.x * 256 + tid;
    const int b   = pix >> 12;
    const int p   = pix & 4095;
    const float* xb = X + (size_t)b * (DIM * HW) + p;

    float x[DIM];
#pragma unroll
    for (int d = 0; d < DIM; ++d) {
        const float* a = xb + (size_t)d * HW;
        asm volatile("global_load_dword %0, %1, off"
                     : "=v"(x[d]) : "v"(a));
    }
    asm volatile("s_waitcnt vmcnt(0)" ::: "memory");
    __builtin_amdgcn_sched_barrier(0);

    float r[8];
#pragma unroll
    for (int k = 0; k < 8; ++k) r[k] = __fmul_rn(x[k], x[k]);
#pragma unroll
    for (int i = 8; i < DIM; i += 8)
#pragma unroll
        for (int k = 0; k < 8; ++k)
            r[k] = __fadd_rn(r[k], __fmul_rn(x[i + k], x[i + k]));
    const float ff = __fadd_rn(
        __fadd_rn(__fadd_rn(r[0], r[1]), __fadd_rn(r[2], r[3])),
        __fadd_rn(__fadd_rn(r[4], r[5]), __fadd_rn(r[6], r[7])));

    float minv = __builtin_inff();
    int   mini = 0;
#pragma unroll 1
    for (int j0 = 0; j0 < NEMB; j0 += 4) {
        const float* e = eT + (size_t)j0 * DIM;
        float a0 = 0.f, a1 = 0.f, a2 = 0.f, a3 = 0.f;
#pragma unroll
        for (int d = 0; d < DIM; ++d) {
            const float xd = x[d];
            a0 = fmaf(xd, e[d],           a0);
            a1 = fmaf(xd, e[DIM + d],     a1);
            a2 = fmaf(xd, e[2 * DIM + d], a2);
            a3 = fmaf(xd, e[3 * DIM + d], a3);
        }
        const float d0 = __fadd_rn(__fsub_rn(ff, __fmul_rn(2.f, a0)), cn[j0 + 0]);
        const float d1 = __fadd_rn(__fsub_rn(ff, __fmul_rn(2.f, a1)), cn[j0 + 1]);
        const float d2 = __fadd_rn(__fsub_rn(ff, __fmul_rn(2.f, a2)), cn[j0 + 2]);
        const float d3 = __fadd_rn(__fsub_rn(ff, __fmul_rn(2.f, a3)), cn[j0 + 3]);
        if (d0 < minv) { minv = d0; mini = j0 + 0; }
        if (d1 < minv) { minv = d1; mini = j0 + 1; }
        if (d2 < minv) { minv = d2; mini = j0 + 2; }
        if (d3 < minv) { minv = d3; mini = j0 + 3; }
    }

    float lerr = 0.f;
    float* outb = OUT + (size_t)b * (DIM * HW) + p;
#pragma unroll
    for (int d = 0; d < DIM; ++d) {
        const float qv = embed[d * NEMB + mini];
        const float df = __fsub_rn(qv, x[d]);
        outb[(size_t)d * HW] = __fadd_rn(x[d], df);
        lerr = fmaf(df, df, lerr);
    }

    __shared__ float sred[256];
    sred[tid] = lerr;
    __syncthreads();
#pragma unroll
    for (int s = 128; s > 0; s >>= 1) {
        if (tid < s) sred[tid] += sred[tid + s];
        __syncthreads();
    }
    if (tid == 0)
        atomicAdd(loss, sred[0] * (1.0f / (float)NOUT));
}

extern "C" void kernel_launch(void* const* d_in, const int* in_sizes, int n_in,
                              void* d_out, int out_size, void* d_ws, size_t ws_size,
                              hipStream_t stream) {
    const float* X = (const float*)d_in[0];
    const float* E = (const float*)d_in[1];
    float* OUT  = (float*)d_out;
    float* loss = OUT + NOUT;

    // ws layout: [cand: NSPLIT*NPIX u64][eT: 1024*64 f32][cn: 1024 f32]
    const size_t cand_bytes = (size_t)NSPLIT * NPIX * 8;
    const size_t need = cand_bytes + (size_t)(NEMB * DIM + NEMB) * 4;

    hipMemsetAsync(loss, 0, sizeof(float), stream);

    if (ws_size >= need) {
        unsigned long long* cand = (unsigned long long*)d_ws;
        float* eT = (float*)((char*)d_ws + cand_bytes);
        float* cn = eT + NEMB * DIM;
        prep_kernel<<<NEMB / 256, 256, 0, stream>>>(E, eT, cn);
        scan_kernel<<<dim3(NPIX / 256, NSPLIT), 256, 0, stream>>>(X, eT, cn, cand);
        finish_kernel<<<NPIX / 256, 256, 0, stream>>>(X, E, cand, OUT, loss);
    } else {
        float* eT = (float*)d_ws;
        float* cn = eT + NEMB * DIM;
        prep_kernel<<<NEMB / 256, 256, 0, stream>>>(E, eT, cn);
        vq_full<<<NPIX / 256, 256, 0, stream>>>(X, E, eT, cn, OUT, loss);
    }
}

// Round 6
// 323.003 us; speedup vs baseline: 1.0546x; 1.0197x over previous
//
#include <hip/hip_runtime.h>

#define DIM    64
#define NEMB   1024
#define HW     4096      // 64*64
#define NPIX   131072    // 32*64*64
#define NOUT   8388608   // 32*64*64*64
#define NSPLIT 4
#define CPS    (NEMB / NSPLIT)   // 256 codes per split

// ---------------------------------------------------------------------------
// prep: eT[j][d] = embed[d][j]  (code rows contiguous -> scalar s_load path),
// cn[j] = ||e_j||^2 with numpy axis-0 semantics (rounded muls, sequential adds)
// ---------------------------------------------------------------------------
__global__ __launch_bounds__(256) void prep_kernel(const float* __restrict__ embed,
                                                   float* __restrict__ eT,
                                                   float* __restrict__ cn) {
    const int j = blockIdx.x * 256 + threadIdx.x;
    if (j >= NEMB) return;
    float v[DIM];
#pragma unroll
    for (int d = 0; d < DIM; ++d) {
        v[d] = embed[d * NEMB + j];
        eT[j * DIM + d] = v[d];
    }
    float s = __fmul_rn(v[0], v[0]);
#pragma unroll
    for (int d = 1; d < DIM; ++d)
        s = __fadd_rn(s, __fmul_rn(v[d], v[d]));
    cn[j] = s;
}

// ---------------------------------------------------------------------------
// scan: block = 256 pixels, blockIdx.y = code split (block-uniform -> e rows
// via scalar s_load pipe).
//
// amdgpu_waves_per_eu(4,4): the MAX bound caps the scheduler's occupancy
// target at 4 waves/EU -> register-pressure target 128 VGPR. Without it the
// backend aims for 8+ waves and remats (R2/R3, VGPR=44) or spills (R4,
// VGPR=36) the 64 x-values instead of keeping them resident. The volatile
// asm loads additionally forbid rematerialization (a volatile def cannot be
// re-executed). Rule #18: explicit vmcnt(0) + sched_barrier(0) before use.
//
// Distance arithmetic identical to the R0-passing kernel. Result: packed
// (dist_bits<<32 | idx) so u64-min = (min dist, first-occurrence tie).
// ---------------------------------------------------------------------------
__global__ __launch_bounds__(256)
__attribute__((amdgpu_waves_per_eu(4, 4)))
void scan_kernel(const float* __restrict__ X,
                 const float* __restrict__ eT,
                 const float* __restrict__ cn,
                 unsigned long long* __restrict__ cand) {
    const int tid = threadIdx.x;
    const int pix = blockIdx.x * 256 + tid;
    const int b   = pix >> 12;
    const int p   = pix & 4095;
    const float* xb = X + (size_t)b * (DIM * HW) + p;

    float x[DIM];
#pragma unroll
    for (int d = 0; d < DIM; ++d) {
        const float* a = xb + (size_t)d * HW;        // coalesced across lanes
        asm volatile("global_load_dword %0, %1, off"
                     : "=v"(x[d]) : "v"(a));
    }
    asm volatile("s_waitcnt vmcnt(0)" ::: "memory");
    __builtin_amdgcn_sched_barrier(0);               // rule #18: no hoist past wait

    // ||f||^2, numpy pairwise 8-accumulator pattern (n=64)
    float r[8];
#pragma unroll
    for (int k = 0; k < 8; ++k) r[k] = __fmul_rn(x[k], x[k]);
#pragma unroll
    for (int i = 8; i < DIM; i += 8)
#pragma unroll
        for (int k = 0; k < 8; ++k)
            r[k] = __fadd_rn(r[k], __fmul_rn(x[i + k], x[i + k]));
    const float ff = __fadd_rn(
        __fadd_rn(__fadd_rn(r[0], r[1]), __fadd_rn(r[2], r[3])),
        __fadd_rn(__fadd_rn(r[4], r[5]), __fadd_rn(r[6], r[7])));

    float minv = __builtin_inff();
    int   mini = 0;
    const int jbase = blockIdx.y * CPS;   // block-uniform

#pragma unroll 1
    for (int jj = 0; jj < CPS; jj += 4) {
        const int j0 = jbase + jj;
        const float* e = eT + (size_t)j0 * DIM;   // block-uniform -> s_load
        float a0 = 0.f, a1 = 0.f, a2 = 0.f, a3 = 0.f;
#pragma unroll
        for (int d = 0; d < DIM; ++d) {
            const float xd = x[d];
            a0 = fmaf(xd, e[d],           a0);   // v_fmac_f32 vacc, s_e, v_x
            a1 = fmaf(xd, e[DIM + d],     a1);
            a2 = fmaf(xd, e[2 * DIM + d], a2);
            a3 = fmaf(xd, e[3 * DIM + d], a3);
        }
        const float d0 = __fadd_rn(__fsub_rn(ff, __fmul_rn(2.f, a0)), cn[j0 + 0]);
        const float d1 = __fadd_rn(__fsub_rn(ff, __fmul_rn(2.f, a1)), cn[j0 + 1]);
        const float d2 = __fadd_rn(__fsub_rn(ff, __fmul_rn(2.f, a2)), cn[j0 + 2]);
        const float d3 = __fadd_rn(__fsub_rn(ff, __fmul_rn(2.f, a3)), cn[j0 + 3]);
        if (d0 < minv) { minv = d0; mini = j0 + 0; }
        if (d1 < minv) { minv = d1; mini = j0 + 1; }
        if (d2 < minv) { minv = d2; mini = j0 + 2; }
        if (d3 < minv) { minv = d3; mini = j0 + 3; }
    }

    cand[(size_t)blockIdx.y * NPIX + pix] =
        ((unsigned long long)__float_as_uint(minv) << 32) | (unsigned)mini;
}

// ---------------------------------------------------------------------------
// finish: merge NSPLIT candidates per pixel, gather code, write q_out =
// x + (q - x), accumulate MSE loss.
// ---------------------------------------------------------------------------
__global__ __launch_bounds__(256) void finish_kernel(const float* __restrict__ X,
                                                     const float* __restrict__ embed,
                                                     const unsigned long long* __restrict__ cand,
                                                     float* __restrict__ OUT,
                                                     float* __restrict__ loss) {
    const int tid = threadIdx.x;
    const int pix = blockIdx.x * 256 + tid;
    const int b   = pix >> 12;
    const int p   = pix & 4095;

    unsigned long long m = cand[pix];
#pragma unroll
    for (int s = 1; s < NSPLIT; ++s) {
        const unsigned long long c = cand[(size_t)s * NPIX + pix];
        m = (c < m) ? c : m;
    }
    const int idx = (int)(m & 0xFFFFFFFFull);

    const float* xb  = X   + (size_t)b * (DIM * HW) + p;
    float*      outb = OUT + (size_t)b * (DIM * HW) + p;
    float lerr = 0.f;
#pragma unroll
    for (int d = 0; d < DIM; ++d) {
        const float qv = embed[d * NEMB + idx];   // 256 KB, L2-resident gather
        const float xv = xb[(size_t)d * HW];
        const float df = __fsub_rn(qv, xv);
        outb[(size_t)d * HW] = __fadd_rn(xv, df); // coalesced across lanes
        lerr = fmaf(df, df, lerr);
    }

    __shared__ float sred[256];
    sred[tid] = lerr;
    __syncthreads();
#pragma unroll
    for (int s = 128; s > 0; s >>= 1) {
        if (tid < s) sred[tid] += sred[tid + s];
        __syncthreads();
    }
    if (tid == 0)
        atomicAdd(loss, sred[0] * (1.0f / (float)NOUT));
}

// ---------------------------------------------------------------------------
// fallback (ws too small for candidates): fused structure, full 1024 scan.
// ---------------------------------------------------------------------------
__global__ __launch_bounds__(256)
__attribute__((amdgpu_waves_per_eu(4, 4)))
void vq_full(const float* __restrict__ X,
             const float* __restrict__ embed,
             const float* __restrict__ eT,
             const float* __restrict__ cn,
             float* __restrict__ OUT,
             float* __restrict__ loss) {
    const int tid = threadIdx.x;
    const int pix = blockIdx.x * 256 + tid;
    const int b   = pix >> 12;
    const int p   = pix & 4095;
    const float* xb = X + (size_t)b * (DIM * HW) + p;

    float x[DIM];
#pragma unroll
    for (int d = 0; d < DIM; ++d) {
        const float* a = xb + (size_t)d * HW;
        asm volatile("global_load_dword %0, %1, off"
                     : "=v"(x[d]) : "v"(a));
    }
    asm volatile("s_waitcnt vmcnt(0)" ::: "memory");
    __builtin_amdgcn_sched_barrier(0);

    float r[8];
#pragma unroll
    for (int k = 0; k < 8; ++k) r[k] = __fmul_rn(x[k], x[k]);
#pragma unroll
    for (int i = 8; i < DIM; i += 8)
#pragma unroll
        for (int k = 0; k < 8; ++k)
            r[k] = __fadd_rn(r[k], __fmul_rn(x[i + k], x[i + k]));
    const float ff = __fadd_rn(
        __fadd_rn(__fadd_rn(r[0], r[1]), __fadd_rn(r[2], r[3])),
        __fadd_rn(__fadd_rn(r[4], r[5]), __fadd_rn(r[6], r[7])));

    float minv = __builtin_inff();
    int   mini = 0;
#pragma unroll 1
    for (int j0 = 0; j0 < NEMB; j0 += 4) {
        const float* e = eT + (size_t)j0 * DIM;
        float a0 = 0.f, a1 = 0.f, a2 = 0.f, a3 = 0.f;
#pragma unroll
        for (int d = 0; d < DIM; ++d) {
            const float xd = x[d];
            a0 = fmaf(xd, e[d],           a0);
            a1 = fmaf(xd, e[DIM + d],     a1);
            a2 = fmaf(xd, e[2 * DIM + d], a2);
            a3 = fmaf(xd, e[3 * DIM + d], a3);
        }
        const float d0 = __fadd_rn(__fsub_rn(ff, __fmul_rn(2.f, a0)), cn[j0 + 0]);
        const float d1 = __fadd_rn(__fsub_rn(ff, __fmul_rn(2.f, a1)), cn[j0 + 1]);
        const float d2 = __fadd_rn(__fsub_rn(ff, __fmul_rn(2.f, a2)), cn[j0 + 2]);
        const float d3 = __fadd_rn(__fsub_rn(ff, __fmul_rn(2.f, a3)), cn[j0 + 3]);
        if (d0 < minv) { minv = d0; mini = j0 + 0; }
        if (d1 < minv) { minv = d1; mini = j0 + 1; }
        if (d2 < minv) { minv = d2; mini = j0 + 2; }
        if (d3 < minv) { minv = d3; mini = j0 + 3; }
    }

    float lerr = 0.f;
    float* outb = OUT + (size_t)b * (DIM * HW) + p;
#pragma unroll
    for (int d = 0; d < DIM; ++d) {
        const float qv = embed[d * NEMB + mini];
        const float df = __fsub_rn(qv, x[d]);
        outb[(size_t)d * HW] = __fadd_rn(x[d], df);
        lerr = fmaf(df, df, lerr);
    }

    __shared__ float sred[256];
    sred[tid] = lerr;
    __syncthreads();
#pragma unroll
    for (int s = 128; s > 0; s >>= 1) {
        if (tid < s) sred[tid] += sred[tid + s];
        __syncthreads();
    }
    if (tid == 0)
        atomicAdd(loss, sred[0] * (1.0f / (float)NOUT));
}

extern "C" void kernel_launch(void* const* d_in, const int* in_sizes, int n_in,
                              void* d_out, int out_size, void* d_ws, size_t ws_size,
                              hipStream_t stream) {
    const float* X = (const float*)d_in[0];
    const float* E = (const float*)d_in[1];
    float* OUT  = (float*)d_out;
    float* loss = OUT + NOUT;

    // ws layout: [cand: NSPLIT*NPIX u64][eT: 1024*64 f32][cn: 1024 f32]
    const size_t cand_bytes = (size_t)NSPLIT * NPIX * 8;
    const size_t need = cand_bytes + (size_t)(NEMB * DIM + NEMB) * 4;

    hipMemsetAsync(loss, 0, sizeof(float), stream);

    if (ws_size >= need) {
        unsigned long long* cand = (unsigned long long*)d_ws;
        float* eT = (float*)((char*)d_ws + cand_bytes);
        float* cn = eT + NEMB * DIM;
        prep_kernel<<<NEMB / 256, 256, 0, stream>>>(E, eT, cn);
        scan_kernel<<<dim3(NPIX / 256, NSPLIT), 256, 0, stream>>>(X, eT, cn, cand);
        finish_kernel<<<NPIX / 256, 256, 0, stream>>>(X, E, cand, OUT, loss);
    } else {
        float* eT = (float*)d_ws;
        float* cn = eT + NEMB * DIM;
        prep_kernel<<<NEMB / 256, 256, 0, stream>>>(E, eT, cn);
        vq_full<<<NPIX / 256, 256, 0, stream>>>(X, E, eT, cn, OUT, loss);
    }
}

// Round 7
// 198.766 us; speedup vs baseline: 1.7138x; 1.6250x over previous
//
#include <hip/hip_runtime.h>

#define DIM   64
#define NEMB  1024
#define HW    4096      // 64*64
#define NPIX  131072    // 32*64*64
#define NOUT  8388608   // 32*64*64*64
#define TILE  256       // pixels per block
#define JC    16        // codes per register tile
#define CPS   256       // codes per wave (4 waves cover 1024)

// ---------------------------------------------------------------------------
// prep: cn[j] = ||e_j||^2, numpy axis-0 semantics (rounded muls, sequential
// adds). No transpose needed anymore: the scan consumes embed[d][j] directly
// (contiguous in j -> scalar s_load_dwordx of 16 codes per d).
// ---------------------------------------------------------------------------
__global__ __launch_bounds__(256) void prep_kernel(const float* __restrict__ embed,
                                                   float* __restrict__ cn) {
    const int j = blockIdx.x * 256 + threadIdx.x;
    if (j >= NEMB) return;
    float v = embed[j];
    float s = __fmul_rn(v, v);
#pragma unroll
    for (int d = 1; d < DIM; ++d) {
        v = embed[d * NEMB + j];
        s = __fadd_rn(s, __fmul_rn(v, v));
    }
    cn[j] = s;
}

// ---------------------------------------------------------------------------
// fused VQ kernel. Block = 256 pixels staged in LDS (R2-R5 lesson: the
// backend will never keep x[64] resident in VGPRs; LDS is the placement the
// compiler can't defeat). 4 waves x 256-code ranges; readfirstlane forces
// the code base scalar so e-loads use the s_load pipe (R1 lesson). Each
// lane: 4 pixels x 16 codes register tile, ds_read_b128 per d (conflict-
// free), 64 v_fmac per d. Distance arithmetic identical to the R0-passing
// kernel; packed-u64 min merge = exact first-occurrence argmin.
// ---------------------------------------------------------------------------
__global__ __launch_bounds__(256, 2)
void vq_kernel(const float* __restrict__ X,
               const float* __restrict__ embed,
               const float* __restrict__ cn,
               float* __restrict__ OUT,
               float* __restrict__ loss) {
    __shared__ float x_lds[DIM][TILE];            // 64 KB
    __shared__ float ff_lds[TILE];                // 1 KB
    __shared__ unsigned long long sm[4 * TILE];   // 8 KB
    __shared__ float sred[256];                   // 1 KB

    const int tid  = threadIdx.x;
    const int l    = tid & 63;
    const int w    = tid >> 6;
    const int pix0 = blockIdx.x * TILE;
    const int b    = pix0 >> 12;        // 256 | 4096 -> same image per block
    const int p0   = pix0 & 4095;

    // ---- stage: thread t owns pixel t; loads its 64 d-values (coalesced
    //      across t per d), writes LDS (conflict-free), computes ||f||^2
    //      with the numpy pairwise-8 pattern from its own register copies.
    {
        const float* xb = X + (size_t)b * (DIM * HW) + p0 + tid;
        float rr[8];
#pragma unroll
        for (int i = 0; i < 8; ++i) {
            const float v = xb[(size_t)i * HW];
            x_lds[i][tid] = v;
            rr[i] = __fmul_rn(v, v);
        }
#pragma unroll
        for (int i = 8; i < DIM; i += 8)
#pragma unroll
            for (int q = 0; q < 8; ++q) {
                const float v = xb[(size_t)(i + q) * HW];
                x_lds[i + q][tid] = v;
                rr[q] = __fadd_rn(rr[q], __fmul_rn(v, v));
            }
        ff_lds[tid] = __fadd_rn(
            __fadd_rn(__fadd_rn(rr[0], rr[1]), __fadd_rn(rr[2], rr[3])),
            __fadd_rn(__fadd_rn(rr[4], rr[5]), __fadd_rn(rr[6], rr[7])));
    }
    __syncthreads();

    // ---- scan: wave w covers codes [w*CPS, w*CPS+CPS) for pixels 4l..4l+3
    const int jbase = __builtin_amdgcn_readfirstlane(w * CPS);  // manifest-scalar
    float ff[4];
#pragma unroll
    for (int k = 0; k < 4; ++k) ff[k] = ff_lds[4 * l + k];

    float minv[4] = {__builtin_inff(), __builtin_inff(),
                     __builtin_inff(), __builtin_inff()};
    int mini[4] = {0, 0, 0, 0};

#pragma unroll 1
    for (int g = 0; g < CPS / JC; ++g) {
        const int j0 = jbase + g * JC;
        float acc[4][JC];
#pragma unroll
        for (int k = 0; k < 4; ++k)
#pragma unroll
            for (int c = 0; c < JC; ++c) acc[k][c] = 0.f;

        const float* erow = embed + j0;     // scalar base
#pragma unroll 4
        for (int d = 0; d < DIM; ++d) {
            const float4 x4 = *reinterpret_cast<const float4*>(&x_lds[d][4 * l]);
#pragma unroll
            for (int c = 0; c < JC; ++c) {
                const float ev = erow[(size_t)d * NEMB + c];   // s_load, 16 contiguous
                acc[0][c] = fmaf(x4.x, ev, acc[0][c]);   // sequential-d chain per
                acc[1][c] = fmaf(x4.y, ev, acc[1][c]);   // (pix,code) == R0 order
                acc[2][c] = fmaf(x4.z, ev, acc[2][c]);
                acc[3][c] = fmaf(x4.w, ev, acc[3][c]);
            }
        }
#pragma unroll
        for (int c = 0; c < JC; ++c) {
            const float cnj = cn[j0 + c];
#pragma unroll
            for (int k = 0; k < 4; ++k) {
                const float dist =
                    __fadd_rn(__fsub_rn(ff[k], __fmul_rn(2.f, acc[k][c])), cnj);
                if (dist < minv[k]) { minv[k] = dist; mini[k] = j0 + c; }  // strict <
            }
        }
    }

#pragma unroll
    for (int k = 0; k < 4; ++k)
        sm[w * TILE + 4 * l + k] =
            ((unsigned long long)__float_as_uint(minv[k]) << 32) | (unsigned)mini[k];
    __syncthreads();

    // ---- merge 4 waves (dist>0 -> bit order valid; low-32 idx -> ties pick
    //      the smaller index = np.argmin first occurrence)
    unsigned long long m = sm[tid];
#pragma unroll
    for (int s = 1; s < 4; ++s) {
        const unsigned long long c2 = sm[s * TILE + tid];
        m = (c2 < m) ? c2 : m;
    }
    const int idx = (int)(m & 0xFFFFFFFFull);

    // ---- output + loss: thread t owns pixel t; x from LDS (bank-free),
    //      embed gather is L2-resident (256 KB), writes coalesced.
    float lerr = 0.f;
    float* outb = OUT + (size_t)b * (DIM * HW) + p0 + tid;
#pragma unroll 8
    for (int d = 0; d < DIM; ++d) {
        const float qv = embed[d * NEMB + idx];
        const float xv = x_lds[d][tid];
        const float df = __fsub_rn(qv, xv);
        outb[(size_t)d * HW] = __fadd_rn(xv, df);
        lerr = fmaf(df, df, lerr);
    }

    sred[tid] = lerr;
    __syncthreads();
#pragma unroll
    for (int s = 128; s > 0; s >>= 1) {
        if (tid < s) sred[tid] += sred[tid + s];
        __syncthreads();
    }
    if (tid == 0)
        atomicAdd(loss, sred[0] * (1.0f / (float)NOUT));
}

extern "C" void kernel_launch(void* const* d_in, const int* in_sizes, int n_in,
                              void* d_out, int out_size, void* d_ws, size_t ws_size,
                              hipStream_t stream) {
    const float* X = (const float*)d_in[0];
    const float* E = (const float*)d_in[1];
    float* OUT  = (float*)d_out;
    float* loss = OUT + NOUT;
    float* cn   = (float*)d_ws;    // 1024 floats

    hipMemsetAsync(loss, 0, sizeof(float), stream);
    prep_kernel<<<NEMB / 256, 256, 0, stream>>>(E, cn);
    vq_kernel<<<NPIX / TILE, 256, 0, stream>>>(X, E, cn, OUT, loss);
}